// Round 3
// baseline (3309.710 us; speedup 1.0000x reference)
//
#include <hip/hip_runtime.h>
#include <cstdint>
#include <cstddef>

// Problem constants (reference: T,B,H_IN,H_HID = 2048,64,256,256)
#define T_LEN 2048
#define B_N   64
#define H_INP 256
#define H_HID 256
#define G3    768              // 3*H_HID (gates r,z,n)
#define M_ROWS (T_LEN * B_N)   // 131072
#define SCH   16               // scan steps per LDS chunk

typedef _Float16 f16;
typedef _Float16 f16x2 __attribute__((ext_vector_type(2)));
typedef _Float16 f16x8 __attribute__((ext_vector_type(8)));
typedef float    f32x4 __attribute__((ext_vector_type(4)));

static __device__ __forceinline__ float fdot2f(uint32_t a, uint32_t b, float c) {
#if __has_builtin(__builtin_amdgcn_fdot2)
  return __builtin_amdgcn_fdot2(__builtin_bit_cast(f16x2, a),
                                __builtin_bit_cast(f16x2, b), c, false);
#else
  f16x2 av = __builtin_bit_cast(f16x2, a);
  f16x2 bv = __builtin_bit_cast(f16x2, b);
  return c + (float)av.x * (float)bv.x + (float)av.y * (float)bv.y;
#endif
}

// ---------------------------------------------------------------- zero d_out
__global__ void k_zero(float4* __restrict__ p, int n4) {
  int i = blockIdx.x * blockDim.x + threadIdx.x;
  int stride = gridDim.x * blockDim.x;
  float4 z; z.x = z.y = z.z = z.w = 0.f;
  for (; i < n4; i += stride) p[i] = z;
}

// ------------------------------------------------------------- f32 -> f16
__global__ void k_cvt(const float2* __restrict__ s, f16x2* __restrict__ d, int n2) {
  int i = blockIdx.x * blockDim.x + threadIdx.x;
  int stride = gridDim.x * blockDim.x;
  for (; i < n2; i += stride) {
    float2 v = s[i];
    f16x2 p; p.x = (f16)v.x; p.y = (f16)v.y;
    d[i] = p;
  }
}

// ---------------------------------------------- per-column pack: tidx, lens
__global__ __launch_bounds__(64) void k_prep_col(const int* __restrict__ mask,
                                                 unsigned short* __restrict__ tidx,
                                                 int* __restrict__ lens) {
  const int b = blockIdx.x;
  const int lane = threadIdx.x;
  unsigned short* tp = tidx + b * T_LEN;
  int base = 0;
  for (int c = 0; c < T_LEN / 64; ++c) {
    int t = c * 64 + lane;
    bool m = mask[t * B_N + b] != 0;
    unsigned long long bal = __ballot(m);
    int pc = __popcll(bal & ((1ull << lane) - 1ull));
    if (m) tp[base + pc] = (unsigned short)t;
    base += __popcll(bal);
  }
  if (lane == 0) lens[b] = base;
}

// --------------------------------------------------- per-row true counts
__global__ __launch_bounds__(256) void k_rowcnt(const int* __restrict__ mask,
                                                int* __restrict__ rowcnt) {
  int g = blockIdx.x * 256 + threadIdx.x;
  int t = g >> 6, lane = g & 63;
  bool m = mask[t * B_N + lane] != 0;
  unsigned long long bal = __ballot(m);
  if (lane == 0) rowcnt[t] = __popcll(bal);
}

// ------------------------------------------- exclusive prefix of rowcnt[2048]
__global__ __launch_bounds__(512) void k_rowpref(const int* __restrict__ rowcnt,
                                                 int* __restrict__ rowpref,
                                                 int* __restrict__ ntru) {
  const int tid = threadIdx.x;
  const int lane = tid & 63, w = tid >> 6;
  int4 v = ((const int4*)rowcnt)[tid];
  int s = v.x + v.y + v.z + v.w;
  int incl = s;
  for (int d = 1; d < 64; d <<= 1) {
    int t = __shfl_up(incl, d, 64);
    if (lane >= d) incl += t;
  }
  __shared__ int wt[8], wo[8];
  if (lane == 63) wt[w] = incl;
  __syncthreads();
  if (tid == 0) {
    int run = 0;
    for (int i = 0; i < 8; ++i) { wo[i] = run; run += wt[i]; }
    ntru[0] = run;
  }
  __syncthreads();
  int base = wo[w] + incl - s;
  int4 o; o.x = base; o.y = base + v.x; o.z = o.y + v.y; o.w = o.z + v.z;
  ((int4*)rowpref)[tid] = o;
}

// --------------------------------------------------- inverse permutation
__global__ __launch_bounds__(256) void k_inv(const int* __restrict__ mask,
                                             const int* __restrict__ rowpref,
                                             int* __restrict__ inv) {
  int g = blockIdx.x * 256 + threadIdx.x;
  int t = g >> 6, lane = g & 63;
  bool m = mask[t * B_N + lane] != 0;
  unsigned long long bal = __ballot(m);
  int r = rowpref[t] + __popcll(bal & ((1ull << lane) - 1ull));
  if (m) inv[r] = t * B_N + lane;
}

// ------------------------------------------- gi = X @ W_ih^T + b_ih (f16 MFMA)
__global__ __launch_bounds__(256) void k_gemm(const f16* __restrict__ X,
                                              const f16* __restrict__ W,
                                              const float* __restrict__ bias,
                                              f16* __restrict__ GI) {
  const int lane = threadIdx.x & 63;
  const int wave = threadIdx.x >> 6;
  const int m0 = blockIdx.x * 64 + wave * 16;
  const int n0 = blockIdx.y * 64;
  const int idx16 = lane & 15;
  const int kofs  = (lane >> 4) * 8;

  const f16* ap  = X + (size_t)(m0 + idx16) * H_INP + kofs;
  const f16* bp0 = W + (size_t)(n0 + idx16) * H_INP + kofs;

  f32x4 acc[4] = { {0,0,0,0}, {0,0,0,0}, {0,0,0,0}, {0,0,0,0} };
#pragma unroll
  for (int kt = 0; kt < 8; ++kt) {
    f16x8 a = *(const f16x8*)(ap + kt * 32);
#pragma unroll
    for (int nt = 0; nt < 4; ++nt) {
      f16x8 bb = *(const f16x8*)(bp0 + (size_t)nt * 16 * H_INP + kt * 32);
      acc[nt] = __builtin_amdgcn_mfma_f32_16x16x32_f16(a, bb, acc[nt], 0, 0, 0);
    }
  }
  const int mbase = m0 + (lane >> 4) * 4;
#pragma unroll
  for (int nt = 0; nt < 4; ++nt) {
    const int col = n0 + nt * 16 + idx16;
    const float bv = bias[col];
#pragma unroll
    for (int r = 0; r < 4; ++r)
      GI[(size_t)(mbase + r) * G3 + col] = (f16)(acc[nt][r] + bv);
  }
}

// -------------------------------------------------- GRU scan, 1 column / block
// 768 threads = 12 waves. Thread j owns W_hh row j: 256 f16 = 128 dwords in
// VGPRs (launch_bounds(768,3) -> 170-reg budget keeps them out of AGPRs).
// gh[j] = fdot2 chain with h broadcast via uniform-address ds_read_b128 (LGKM
// pipe, co-issues with VALU; no readlane). Rows 0..255 are the r-gate rows and
// live on the gate threads, so only z/n cross through LDS. GI rows / inv / out
// rows staged in LDS per 16-step chunk (no vmem in steady-state steps).
__global__ __launch_bounds__(768, 3) void k_scan(const f16* __restrict__ Whh,
                                                 const f16* __restrict__ GI,
                                                 const float* __restrict__ h0,
                                                 const float* __restrict__ bhh,
                                                 const unsigned short* __restrict__ tidx,
                                                 const int* __restrict__ lens,
                                                 const int* __restrict__ inv,
                                                 const int* __restrict__ ntru,
                                                 float* __restrict__ out) {
  const int b = blockIdx.x;
  const int tid = threadIdx.x;
  const int lane = tid & 63;
  const int wav = tid >> 6;

  __shared__ f16   GIbuf[SCH * G3];      // 24576 B
  __shared__ float outb[SCH * H_HID];    // 16384 B
  __shared__ float ghs[2 * H_HID];       //  2048 B (z rows, then n rows)
  __shared__ f16   hpk[H_HID];           //   512 B
  __shared__ int   ivb[2][SCH];          //   128 B

  // weights: thread tid owns W_hh row tid (dword-packed f16 pairs)
  uint32_t w[128];
  {
    const uint4* wp = (const uint4*)(Whh + (size_t)tid * H_HID);
#pragma unroll
    for (int i = 0; i < 32; ++i) {
      uint4 v = wp[i];
      w[4*i+0] = v.x; w[4*i+1] = v.y; w[4*i+2] = v.z; w[4*i+3] = v.w;
    }
  }
  const float bias = bhh[tid];       // folded into this row's dot product
  float h_reg = 0.f;
  if (tid < H_HID) h_reg = h0[b * H_HID + tid];
  if (tid < H_HID / 2) {
    float2 hv = ((const float2*)(h0 + b * H_HID))[tid];
    f16x2 p; p.x = (f16)hv.x; p.y = (f16)hv.y;
    ((f16x2*)hpk)[tid] = p;
  }
  const int L  = lens[b];
  const int Nt = ntru[0];
  const unsigned short* tptr = tidx + b * T_LEN;
  __syncthreads();

  for (int k = 0; k < L; ++k) {
    if ((k & (SCH - 1)) == 0) {
      const int par = (k >> 4) & 1;
      if (k > 0) {  // flush previous chunk's output rows
        for (int r = wav; r < SCH; r += 12) {
          int iv = ivb[par ^ 1][r];
          if (iv >= 0)
            *(float4*)(out + (size_t)iv * H_HID + (lane << 2)) =
                *(const float4*)(outb + r * H_HID + (lane << 2));
        }
      }
      {  // refill GI chunk + inv
        int nrows = L - k; if (nrows > SCH) nrows = SCH;
        int r = tid / 48, c = tid % 48;   // 16 rows x 48 chunks of 32 B
        if (r < nrows) {
          int t = tptr[k + r];
          const uint4* src = (const uint4*)(GI + ((size_t)t * B_N + b) * G3) + (c << 1);
          uint4 v0 = src[0], v1 = src[1];
          uint4* dst = (uint4*)(GIbuf + r * G3) + (c << 1);
          dst[0] = v0; dst[1] = v1;
        }
        if (tid < SCH) {
          int kk = k + tid;
          int pr = kk * B_N + b;
          ivb[par][tid] = (kk < L && pr < Nt) ? inv[pr] : -1;
        }
      }
      __syncthreads();
    }
    // --- matvec: gh[tid] = W_hh[tid,:] . h + bhh[tid] ---
    float acc0 = bias, acc1 = 0.f;
    {
      const uint4* hb = (const uint4*)hpk;
#pragma unroll
      for (int i = 0; i < 16; ++i) {
        uint4 hv = hb[i];          // uniform address -> LDS broadcast
        acc0 = fdot2f(w[4*i+0], hv.x, acc0);
        acc0 = fdot2f(w[4*i+1], hv.y, acc0);
        acc0 = fdot2f(w[4*i+2], hv.z, acc0);
        acc0 = fdot2f(w[4*i+3], hv.w, acc0);
      }
#pragma unroll
      for (int i = 16; i < 32; ++i) {
        uint4 hv = hb[i];
        acc1 = fdot2f(w[4*i+0], hv.x, acc1);
        acc1 = fdot2f(w[4*i+1], hv.y, acc1);
        acc1 = fdot2f(w[4*i+2], hv.z, acc1);
        acc1 = fdot2f(w[4*i+3], hv.w, acc1);
      }
    }
    const float gh = acc0 + acc1;
    if (tid >= H_HID) ghs[tid - H_HID] = gh;   // publish z and n rows
    __syncthreads();
    // --- gates (threads 0..255; gh of the r-row is local) ---
    if (tid < H_HID) {
      const int slot = k & (SCH - 1);
      const float gi0 = (float)GIbuf[slot * G3 + tid];
      const float gi1 = (float)GIbuf[slot * G3 + H_HID + tid];
      const float gi2 = (float)GIbuf[slot * G3 + 2 * H_HID + tid];
      const float ghz = ghs[tid];
      const float ghn = ghs[H_HID + tid];
      const float rg = __builtin_amdgcn_rcpf(1.f + __expf(-(gi0 + gh)));
      const float zg = __builtin_amdgcn_rcpf(1.f + __expf(-(gi1 + ghz)));
      const float xx = gi2 + rg * ghn;
      const float ng = 1.f - 2.f * __builtin_amdgcn_rcpf(1.f + __expf(2.f * xx));
      const float hn = (1.f - zg) * ng + zg * h_reg;
      h_reg = hn;
      hpk[tid] = (f16)hn;
      outb[slot * H_HID + tid] = hn;
    }
    __syncthreads();
  }
  if (L > 0) {  // tail flush
    const int kb = (L - 1) & ~(SCH - 1);
    const int rows = L - kb;
    const int par = (kb >> 4) & 1;
    for (int r = wav; r < rows; r += 12) {
      int iv = ivb[par][r];
      if (iv >= 0)
        *(float4*)(out + (size_t)iv * H_HID + (lane << 2)) =
            *(const float4*)(outb + r * H_HID + (lane << 2));
    }
  }
  if (tid < H_HID)
    out[(size_t)M_ROWS * H_HID + (size_t)b * H_HID + tid] = h_reg;
}

// ---------------------------------------------------------------------------
extern "C" void kernel_launch(void* const* d_in, const int* in_sizes, int n_in,
                              void* d_out, int out_size, void* d_ws, size_t ws_size,
                              hipStream_t stream) {
  const float* x    = (const float*)d_in[0];
  const float* h0   = (const float*)d_in[1];
  const int*   mask = (const int*)d_in[2];
  const float* wih  = (const float*)d_in[3];
  const float* whh  = (const float*)d_in[4];
  const float* bih  = (const float*)d_in[5];
  const float* bhh  = (const float*)d_in[6];
  float* out = (float*)d_out;

  // workspace layout (~270.3 MB)
  char* ws = (char*)d_ws;
  f16* X16   = (f16*)(ws + 0);                       //  67,108,864 B
  f16* Wih16 = (f16*)(ws + 67108864);                //     393,216 B
  f16* Whh16 = (f16*)(ws + 67502080);                //     393,216 B
  f16* GI    = (f16*)(ws + 67895296);                // 201,326,592 B
  unsigned short* tidx = (unsigned short*)(ws + 269221888);  // 262,144 B
  int* rowcnt  = (int*)(ws + 269484032);             //       8,192 B
  int* rowpref = (int*)(ws + 269492224);             //       8,192 B
  int* inv   = (int*)(ws + 269746176);               //     524,288 B
  int* lens  = (int*)(ws + 270270464);               //         256 B
  int* ntru  = (int*)(ws + 270270720);               //           4 B

  hipLaunchKernelGGL(k_zero, dim3(4096), dim3(256), 0, stream,
                     (float4*)d_out, out_size / 4);
  hipLaunchKernelGGL(k_cvt, dim3(4096), dim3(256), 0, stream,
                     (const float2*)x, (f16x2*)X16, M_ROWS * H_INP / 2);
  hipLaunchKernelGGL(k_cvt, dim3(96), dim3(256), 0, stream,
                     (const float2*)wih, (f16x2*)Wih16, G3 * H_INP / 2);
  hipLaunchKernelGGL(k_cvt, dim3(96), dim3(256), 0, stream,
                     (const float2*)whh, (f16x2*)Whh16, G3 * H_INP / 2);
  hipLaunchKernelGGL(k_prep_col, dim3(B_N), dim3(64), 0, stream,
                     mask, tidx, lens);
  hipLaunchKernelGGL(k_rowcnt, dim3(512), dim3(256), 0, stream, mask, rowcnt);
  hipLaunchKernelGGL(k_rowpref, dim3(1), dim3(512), 0, stream,
                     rowcnt, rowpref, ntru);
  hipLaunchKernelGGL(k_inv, dim3(512), dim3(256), 0, stream,
                     mask, rowpref, inv);
  hipLaunchKernelGGL(k_gemm, dim3(M_ROWS / 64, G3 / 64), dim3(256), 0, stream,
                     X16, Wih16, bih, GI);
  hipLaunchKernelGGL(k_scan, dim3(B_N), dim3(768), 0, stream,
                     Whh16, GI, h0, bhh, tidx, lens, inv, ntru, out);
}